// Round 1
// baseline (9697.895 us; speedup 1.0000x reference)
//
#include <hip/hip_runtime.h>
#include <math.h>

// CLIP surgery RecWithAttnbiasHead — round 0: full fp32 pipeline, correctness-first.
// n=2, c=768, H=12, d=64, S=100, L=1024, N=1125, LY=3, out=512.

constexpr int Cc = 768;
constexpr int Ss = 100;
constexpr int Hh = 12;
constexpr int Ll = 1024;
constexpr int Nn = 1125;
constexpr int NB = 2;
constexpr float NEGV = -100.0f;

// ---------------- assemble token streams ----------------
__global__ __launch_bounds__(256) void assemble_kernel(
    const float* __restrict__ cls, const float* __restrict__ pix,
    const float* __restrict__ sur, float* __restrict__ xo, float* __restrict__ xs) {
  int idx = blockIdx.x * 256 + (int)threadIdx.x;
  int total = NB * Nn * Cc;
  if (idx >= total) return;
  int ch = idx % Cc;
  int t  = (idx / Cc) % Nn;
  int b  = idx / (Cc * Nn);
  float vo, vs;
  if (t <= Ss) vo = cls[b * Cc + ch];
  else         vo = pix[(size_t)b * Cc * Ll + (size_t)ch * Ll + (t - Ss - 1)];
  if (t < Ss)  vs = sur[b * Cc + ch];
  else         vs = sur[(size_t)(t - Ss) * NB * Cc + b * Cc + ch];
  xo[idx] = vo;
  xs[idx] = vs;
}

// ---------------- layer norm (c=768, 256 threads, 3 elems/thread) ----------------
// row r maps to input row b*Nn + row_off + i where b=r/rows_per_b, i=r%rows_per_b.
__global__ __launch_bounds__(256) void ln_kernel(
    const float* __restrict__ X, const float* __restrict__ w, const float* __restrict__ b,
    float* __restrict__ Y, int rows_per_b, int row_off) {
  int r = blockIdx.x;
  int bb = r / rows_per_b;
  int i  = r % rows_per_b;
  const float* x = X + ((size_t)bb * Nn + row_off + i) * Cc;
  float* y = Y + (size_t)r * Cc;
  int tid = (int)threadIdx.x;
  float v0 = x[tid], v1 = x[tid + 256], v2 = x[tid + 512];
  float s = v0 + v1 + v2;
  __shared__ float sbuf[4];
  for (int off = 32; off; off >>= 1) s += __shfl_xor(s, off);
  if ((tid & 63) == 0) sbuf[tid >> 6] = s;
  __syncthreads();
  float mean = (sbuf[0] + sbuf[1] + sbuf[2] + sbuf[3]) * (1.0f / Cc);
  float d0 = v0 - mean, d1 = v1 - mean, d2 = v2 - mean;
  float q = d0 * d0 + d1 * d1 + d2 * d2;
  __syncthreads();
  for (int off = 32; off; off >>= 1) q += __shfl_xor(q, off);
  if ((tid & 63) == 0) sbuf[tid >> 6] = q;
  __syncthreads();
  float var = (sbuf[0] + sbuf[1] + sbuf[2] + sbuf[3]) * (1.0f / Cc);
  float inv = rsqrtf(var + 1e-5f);
  y[tid]       = d0 * inv * w[tid]       + b[tid];
  y[tid + 256] = d1 * inv * w[tid + 256] + b[tid + 256];
  y[tid + 512] = d2 * inv * w[tid + 512] + b[tid + 512];
}

// ---------------- fp32 tiled GEMM ----------------
// out[M,N] = X[M,K] @ W(.T) + bias (+ quickGELU) (+ res)
// wlayout 0: W is [N,K] (use W.T) ; wlayout 1: W is [K,N]
// act 1: quick_gelu after bias, before residual.
__global__ __launch_bounds__(256) void gemm_kernel(
    const float* __restrict__ X, const float* __restrict__ W,
    const float* __restrict__ bias, const float* __restrict__ res,
    float* __restrict__ out, int M, int N, int K, int wlayout, int act) {
  __shared__ float As[16][68];
  __shared__ float Bs[16][68];
  int tid = (int)threadIdx.x;
  int tx = tid & 15, ty = tid >> 4;
  int row0 = blockIdx.y * 64, col0 = blockIdx.x * 64;
  float acc[4][4] = {};
  for (int k0 = 0; k0 < K; k0 += 16) {
    {
      int m = tid >> 2, kk = (tid & 3) << 2;
      float4 v = make_float4(0.f, 0.f, 0.f, 0.f);
      if (row0 + m < M) v = *(const float4*)(X + (size_t)(row0 + m) * K + k0 + kk);
      As[kk][m] = v.x; As[kk + 1][m] = v.y; As[kk + 2][m] = v.z; As[kk + 3][m] = v.w;
    }
    if (wlayout == 0) {
      int o = tid >> 2, kk = (tid & 3) << 2;
      float4 v = *(const float4*)(W + (size_t)(col0 + o) * K + k0 + kk);
      Bs[kk][o] = v.x; Bs[kk + 1][o] = v.y; Bs[kk + 2][o] = v.z; Bs[kk + 3][o] = v.w;
    } else {
      int kk = tid >> 4, o4 = (tid & 15) << 2;
      float4 v = *(const float4*)(W + (size_t)(k0 + kk) * N + col0 + o4);
      *(float4*)&Bs[kk][o4] = v;
    }
    __syncthreads();
#pragma unroll
    for (int kk = 0; kk < 16; ++kk) {
      float4 a = *(const float4*)&As[kk][ty << 2];
      float4 b = *(const float4*)&Bs[kk][tx << 2];
      float av[4] = {a.x, a.y, a.z, a.w};
      float bv[4] = {b.x, b.y, b.z, b.w};
#pragma unroll
      for (int ii = 0; ii < 4; ++ii)
#pragma unroll
        for (int jj = 0; jj < 4; ++jj) acc[ii][jj] = fmaf(av[ii], bv[jj], acc[ii][jj]);
    }
    __syncthreads();
  }
#pragma unroll
  for (int ii = 0; ii < 4; ++ii) {
    int row = row0 + (ty << 2) + ii;
    if (row >= M) continue;
#pragma unroll
    for (int jj = 0; jj < 4; ++jj) {
      int col = col0 + (tx << 2) + jj;
      float v = acc[ii][jj];
      if (bias) v += bias[col];
      if (act == 1) v = v / (1.0f + __expf(-1.702f * v));
      if (res) v += res[(size_t)row * N + col];
      out[(size_t)row * N + col] = v;
    }
  }
}

// ---------------- flash attention (fp32, 1 wave per query row) ----------------
// pass 0: ORI (q,k from qkv, biased mask); pass 1: SUR (q=k=v, plain mask)
__global__ __launch_bounds__(256) void attn_kernel(
    const float* __restrict__ qkv, const float* __restrict__ abias,
    float* __restrict__ outp, int pass) {
  __shared__ float Kt[64][68];
  __shared__ float Vt[64][68];
  __shared__ float qs[4][64];
  __shared__ float ps[4][64];
  int bh = blockIdx.y;
  int b = bh / Hh, h = bh - b * Hh;
  int wave = (int)threadIdx.x >> 6, lane = (int)threadIdx.x & 63;
  int i = blockIdx.x * 4 + wave;
  bool qvalid = i < Nn;
  int qoff = (pass == 0) ? h * 64 : 2 * Cc + h * 64;
  int koff = (pass == 0) ? Cc + h * 64 : 2 * Cc + h * 64;
  int voff = 2 * Cc + h * 64;
  if (qvalid) qs[wave][lane] = qkv[((size_t)b * Nn + i) * 2304 + qoff + lane] * 0.125f;
  float m = -1e30f, lsum = 0.f, oacc = 0.f;
  for (int key0 = 0; key0 < Nn; key0 += 64) {
    __syncthreads();
    for (int idx = (int)threadIdx.x; idx < 64 * 64; idx += 256) {
      int rr = idx >> 6, cc = idx & 63;
      int key = key0 + rr;
      float kv = 0.f, vv = 0.f;
      if (key < Nn) {
        size_t base = ((size_t)b * Nn + key) * 2304;
        kv = qkv[base + koff + cc];
        vv = qkv[base + voff + cc];
      }
      Kt[rr][cc] = kv;
      Vt[rr][cc] = vv;
    }
    __syncthreads();
    if (qvalid) {
      int j = key0 + lane;
      float s = -1e30f;
      if (j < Nn) {
        float dot = 0.f;
#pragma unroll
        for (int kk = 0; kk < 64; ++kk) dot = fmaf(qs[wave][kk], Kt[lane][kk], dot);
        float msk;
        if (i < Ss) {
          if (j < Ss)       msk = (j == i) ? 0.f : NEGV;
          else if (j == Ss) msk = NEGV;
          else              msk = (pass == 0) ? abias[((size_t)b * Ss + i) * Ll + (j - Ss - 1)] : 0.f;
        } else {
          msk = (j < Ss) ? NEGV : 0.f;
        }
        s = dot + msk;
      }
      float tmax = s;
      for (int off = 32; off; off >>= 1) tmax = fmaxf(tmax, __shfl_xor(tmax, off));
      float mnew = fmaxf(m, tmax);
      float fac = __expf(m - mnew);
      float p = (j < Nn) ? __expf(s - mnew) : 0.f;
      float psum = p;
      for (int off = 32; off; off >>= 1) psum += __shfl_xor(psum, off);
      lsum = lsum * fac + psum;
      m = mnew;
      ps[wave][lane] = p;
      float acc = 0.f;
#pragma unroll
      for (int jj = 0; jj < 64; ++jj) acc = fmaf(ps[wave][jj], Vt[jj][lane], acc);
      oacc = oacc * fac + acc;
    }
  }
  if (qvalid) outp[((size_t)b * Nn + i) * Cc + h * 64 + lane] = oacc / lsum;
}

// ---------------- l2norm heads ----------------
__global__ __launch_bounds__(256) void l2norm_sos_kernel(
    const float* __restrict__ Xp, float* __restrict__ out) {
  int r = blockIdx.x;
  int tid = (int)threadIdx.x;
  const float* x = Xp + (size_t)r * 512;
  float v0 = x[tid], v1 = x[tid + 256];
  float s = v0 * v0 + v1 * v1;
  __shared__ float sbuf[4];
  for (int off = 32; off; off >>= 1) s += __shfl_xor(s, off);
  if ((tid & 63) == 0) sbuf[tid >> 6] = s;
  __syncthreads();
  float tot = sbuf[0] + sbuf[1] + sbuf[2] + sbuf[3];
  float inv = 1.0f / fmaxf(sqrtf(tot), 1e-12f);
  out[(size_t)r * 512 + tid]       = v0 * inv;
  out[(size_t)r * 512 + tid + 256] = v1 * inv;
}

__global__ __launch_bounds__(256) void l2norm_img_kernel(
    const float* __restrict__ Xp, float* __restrict__ out) {
  int r = blockIdx.x;           // b*1025 + ti
  int b = r / 1025, ti = r % 1025;
  int tid = (int)threadIdx.x;
  const float* x = Xp + (size_t)r * 512;
  float v0 = x[tid], v1 = x[tid + 256];
  float s = v0 * v0 + v1 * v1;
  __shared__ float sbuf[4];
  for (int off = 32; off; off >>= 1) s += __shfl_xor(s, off);
  if ((tid & 63) == 0) sbuf[tid >> 6] = s;
  __syncthreads();
  float tot = sbuf[0] + sbuf[1] + sbuf[2] + sbuf[3];
  if (ti == 0) return;          // row S (first of 1025) is discarded
  float inv = 1.0f / fmaxf(sqrtf(tot), 1e-12f);
  float* o = out + (size_t)b * 512 * 1024 + (ti - 1);
  o[(size_t)tid * 1024]         = v0 * inv;
  o[(size_t)(tid + 256) * 1024] = v1 * inv;
}

extern "C" void kernel_launch(void* const* d_in, const int* in_sizes, int n_in,
                              void* d_out, int out_size, void* d_ws, size_t ws_size,
                              hipStream_t stream) {
  const float* cls      = (const float*)d_in[0];
  const float* pix      = (const float*)d_in[1];
  const float* sur      = (const float*)d_in[2];
  const float* abias    = (const float*)d_in[3];
  const float* qkv_w    = (const float*)d_in[4];
  const float* qkv_b    = (const float*)d_in[5];
  const float* proj_w   = (const float*)d_in[6];
  const float* proj_b   = (const float*)d_in[7];
  const float* ln1_w    = (const float*)d_in[8];
  const float* ln1_b    = (const float*)d_in[9];
  const float* ln2_w    = (const float*)d_in[10];
  const float* ln2_b    = (const float*)d_in[11];
  const float* fc_w     = (const float*)d_in[12];
  const float* fc_b     = (const float*)d_in[13];
  const float* fc2_w    = (const float*)d_in[14];
  const float* fc2_b    = (const float*)d_in[15];
  const float* lnp_w    = (const float*)d_in[16];
  const float* lnp_b    = (const float*)d_in[17];
  const float* proj_o   = (const float*)d_in[18];
  float* out = (float*)d_out;

  const size_t SZ = (size_t)NB * Nn * Cc;      // 1,728,000
  float* ws  = (float*)d_ws;
  float* xo  = ws;
  float* xs  = xo  + SZ;
  float* tln = xs  + SZ;
  float* big = tln + SZ;                        // qkv (5.18M) / mlp hidden (6.91M)
  float* ao  = big + (size_t)NB * Nn * 4 * Cc;  // attn ORI out
  float* as_ = ao  + SZ;                        // attn SUR out

  assemble_kernel<<<6750, 256, 0, stream>>>(cls, pix, sur, xo, xs);

  for (int l = 0; l < 3; ++l) {
    const float* qw = qkv_w + (size_t)l * 2304 * 768;
    const float* pw = proj_w + (size_t)l * 768 * 768;
    const float* fw = fc_w + (size_t)l * 3072 * 768;
    const float* f2 = fc2_w + (size_t)l * 768 * 3072;

    ln_kernel<<<2250, 256, 0, stream>>>(xo, ln1_w + l * 768, ln1_b + l * 768, tln, Nn, 0);
    gemm_kernel<<<dim3(36, 36), 256, 0, stream>>>(tln, qw, qkv_b + l * 2304, nullptr, big,
                                                  2250, 2304, 768, 0, 0);
    attn_kernel<<<dim3(282, 24), 256, 0, stream>>>(big, abias, ao, 0);
    attn_kernel<<<dim3(282, 24), 256, 0, stream>>>(big, abias, as_, 1);
    gemm_kernel<<<dim3(12, 36), 256, 0, stream>>>(ao, pw, proj_b + l * 768, xo, xo,
                                                  2250, 768, 768, 0, 0);
    gemm_kernel<<<dim3(12, 36), 256, 0, stream>>>(as_, pw, proj_b + l * 768, xs, xs,
                                                  2250, 768, 768, 0, 0);
    ln_kernel<<<2250, 256, 0, stream>>>(xo, ln2_w + l * 768, ln2_b + l * 768, tln, Nn, 0);
    gemm_kernel<<<dim3(48, 36), 256, 0, stream>>>(tln, fw, fc_b + l * 3072, nullptr, big,
                                                  2250, 3072, 768, 0, 1);
    gemm_kernel<<<dim3(12, 36), 256, 0, stream>>>(big, f2, fc2_b + l * 768, xo, xo,
                                                  2250, 768, 3072, 0, 0);
  }

  // heads
  float* sos_ln = tln;
  float* img_ln = tln + (size_t)200 * 768;
  float* sos_pj = big;
  float* img_pj = big + (size_t)200 * 512;
  ln_kernel<<<200, 256, 0, stream>>>(xo, lnp_w, lnp_b, sos_ln, 100, 0);
  ln_kernel<<<2050, 256, 0, stream>>>(xs, lnp_w, lnp_b, img_ln, 1025, 100);
  gemm_kernel<<<dim3(8, 4), 256, 0, stream>>>(sos_ln, proj_o, nullptr, nullptr, sos_pj,
                                              200, 512, 768, 1, 0);
  gemm_kernel<<<dim3(8, 33), 256, 0, stream>>>(img_ln, proj_o, nullptr, nullptr, img_pj,
                                               2050, 512, 768, 1, 0);
  l2norm_sos_kernel<<<200, 256, 0, stream>>>(sos_pj, out);
  l2norm_img_kernel<<<2050, 256, 0, stream>>>(img_pj, out + 102400);
}

// Round 2
// 2310.141 us; speedup vs baseline: 4.1980x; 4.1980x over previous
//
#include <hip/hip_runtime.h>
#include <math.h>

// CLIP surgery RecWithAttnbiasHead — round 2: MFMA bf16 flash attention.
// n=2, c=768, H=12, d=64, S=100, L=1024, N=1125, LY=3, out=512.

constexpr int Cc = 768;
constexpr int Ss = 100;
constexpr int Hh = 12;
constexpr int Ll = 1024;
constexpr int Nn = 1125;
constexpr int NB = 2;
constexpr float NEGV = -100.0f;

typedef __attribute__((ext_vector_type(8))) short short8v;
typedef __attribute__((ext_vector_type(4))) float f32x4;

__device__ inline unsigned short f2bf(float f) {
  unsigned u = __builtin_bit_cast(unsigned int, f);
  unsigned r = u + 0x7fffu + ((u >> 16) & 1u);
  return (unsigned short)(r >> 16);
}

// XOR-swizzled flat index into a [rows][64] bf16 LDS tile (16B-chunk swizzle).
__device__ inline int swz(int row, int col) {
  return (row << 6) + ((((col >> 3) ^ (row & 7)) << 3) | (col & 7));
}

// ---------------- assemble token streams ----------------
__global__ __launch_bounds__(256) void assemble_kernel(
    const float* __restrict__ cls, const float* __restrict__ pix,
    const float* __restrict__ sur, float* __restrict__ xo, float* __restrict__ xs) {
  int idx = blockIdx.x * 256 + (int)threadIdx.x;
  int total = NB * Nn * Cc;
  if (idx >= total) return;
  int ch = idx % Cc;
  int t  = (idx / Cc) % Nn;
  int b  = idx / (Cc * Nn);
  float vo, vs;
  if (t <= Ss) vo = cls[b * Cc + ch];
  else         vo = pix[(size_t)b * Cc * Ll + (size_t)ch * Ll + (t - Ss - 1)];
  if (t < Ss)  vs = sur[b * Cc + ch];
  else         vs = sur[(size_t)(t - Ss) * NB * Cc + b * Cc + ch];
  xo[idx] = vo;
  xs[idx] = vs;
}

// ---------------- layer norm ----------------
__global__ __launch_bounds__(256) void ln_kernel(
    const float* __restrict__ X, const float* __restrict__ w, const float* __restrict__ b,
    float* __restrict__ Y, int rows_per_b, int row_off) {
  int r = blockIdx.x;
  int bb = r / rows_per_b;
  int i  = r % rows_per_b;
  const float* x = X + ((size_t)bb * Nn + row_off + i) * Cc;
  float* y = Y + (size_t)r * Cc;
  int tid = (int)threadIdx.x;
  float v0 = x[tid], v1 = x[tid + 256], v2 = x[tid + 512];
  float s = v0 + v1 + v2;
  __shared__ float sbuf[4];
  for (int off = 32; off; off >>= 1) s += __shfl_xor(s, off);
  if ((tid & 63) == 0) sbuf[tid >> 6] = s;
  __syncthreads();
  float mean = (sbuf[0] + sbuf[1] + sbuf[2] + sbuf[3]) * (1.0f / Cc);
  float d0 = v0 - mean, d1 = v1 - mean, d2 = v2 - mean;
  float q = d0 * d0 + d1 * d1 + d2 * d2;
  __syncthreads();
  for (int off = 32; off; off >>= 1) q += __shfl_xor(q, off);
  if ((tid & 63) == 0) sbuf[tid >> 6] = q;
  __syncthreads();
  float var = (sbuf[0] + sbuf[1] + sbuf[2] + sbuf[3]) * (1.0f / Cc);
  float inv = rsqrtf(var + 1e-5f);
  y[tid]       = d0 * inv * w[tid]       + b[tid];
  y[tid + 256] = d1 * inv * w[tid + 256] + b[tid + 256];
  y[tid + 512] = d2 * inv * w[tid + 512] + b[tid + 512];
}

// ---------------- fp32 tiled GEMM ----------------
__global__ __launch_bounds__(256) void gemm_kernel(
    const float* __restrict__ X, const float* __restrict__ W,
    const float* __restrict__ bias, const float* __restrict__ res,
    float* __restrict__ out, int M, int N, int K, int wlayout, int act) {
  __shared__ float As[16][68];
  __shared__ float Bs[16][68];
  int tid = (int)threadIdx.x;
  int tx = tid & 15, ty = tid >> 4;
  int row0 = blockIdx.y * 64, col0 = blockIdx.x * 64;
  float acc[4][4] = {};
  for (int k0 = 0; k0 < K; k0 += 16) {
    {
      int m = tid >> 2, kk = (tid & 3) << 2;
      float4 v = make_float4(0.f, 0.f, 0.f, 0.f);
      if (row0 + m < M) v = *(const float4*)(X + (size_t)(row0 + m) * K + k0 + kk);
      As[kk][m] = v.x; As[kk + 1][m] = v.y; As[kk + 2][m] = v.z; As[kk + 3][m] = v.w;
    }
    if (wlayout == 0) {
      int o = tid >> 2, kk = (tid & 3) << 2;
      float4 v = *(const float4*)(W + (size_t)(col0 + o) * K + k0 + kk);
      Bs[kk][o] = v.x; Bs[kk + 1][o] = v.y; Bs[kk + 2][o] = v.z; Bs[kk + 3][o] = v.w;
    } else {
      int kk = tid >> 4, o4 = (tid & 15) << 2;
      float4 v = *(const float4*)(W + (size_t)(k0 + kk) * N + col0 + o4);
      *(float4*)&Bs[kk][o4] = v;
    }
    __syncthreads();
#pragma unroll
    for (int kk = 0; kk < 16; ++kk) {
      float4 a = *(const float4*)&As[kk][ty << 2];
      float4 b = *(const float4*)&Bs[kk][tx << 2];
      float av[4] = {a.x, a.y, a.z, a.w};
      float bv[4] = {b.x, b.y, b.z, b.w};
#pragma unroll
      for (int ii = 0; ii < 4; ++ii)
#pragma unroll
        for (int jj = 0; jj < 4; ++jj) acc[ii][jj] = fmaf(av[ii], bv[jj], acc[ii][jj]);
    }
    __syncthreads();
  }
#pragma unroll
  for (int ii = 0; ii < 4; ++ii) {
    int row = row0 + (ty << 2) + ii;
    if (row >= M) continue;
#pragma unroll
    for (int jj = 0; jj < 4; ++jj) {
      int col = col0 + (tx << 2) + jj;
      float v = acc[ii][jj];
      if (bias) v += bias[col];
      if (act == 1) v = v / (1.0f + __expf(-1.702f * v));
      if (res) v += res[(size_t)row * N + col];
      out[(size_t)row * N + col] = v;
    }
  }
}

// ---------------- MFMA bf16 flash attention ----------------
// blockIdx.x: query tile (64 queries, 4 waves x 16), blockIdx.y: b*H+h,
// blockIdx.z: pass (0 = ORI biased, 1 = SUR plain).
__global__ __launch_bounds__(256) void attn_mfma_kernel(
    const float* __restrict__ qkv, const float* __restrict__ abias,
    float* __restrict__ out0, float* __restrict__ out1) {
  __shared__ __align__(16) unsigned short Klds[64 * 64];
  __shared__ __align__(16) unsigned short Vlds[64 * 64];   // transposed [d][key]
  __shared__ __align__(16) unsigned short Plds[4 * 16 * 64]; // per-wave [16][64]
  int pass = blockIdx.z;
  float* outp = pass == 0 ? out0 : out1;
  int bh = blockIdx.y;
  int b = bh / Hh, h = bh - b * Hh;
  int tid = (int)threadIdx.x;
  int wave = tid >> 6, lane = tid & 63;
  int g = lane >> 4, li = lane & 15;
  int qbase = blockIdx.x * 64 + wave * 16;
  int qoff = (pass == 0) ? h * 64 : 2 * Cc + h * 64;
  int koff = (pass == 0) ? Cc + h * 64 : 2 * Cc + h * 64;
  int voff = 2 * Cc + h * 64;
  int v_rel = voff - koff;

  // ---- Q fragments in registers: lane holds Q[qbase+li][kc*32 + g*8 + 0..7] ----
  short8v qf[2];
  {
    int qrow = qbase + li; if (qrow >= Nn) qrow = Nn - 1;
    const float* qp = qkv + ((size_t)b * Nn + qrow) * 2304 + qoff;
#pragma unroll
    for (int kc = 0; kc < 2; ++kc) {
      int d0 = kc * 32 + g * 8;
      float4 a = *(const float4*)(qp + d0);
      float4 c = *(const float4*)(qp + d0 + 4);
      short8v v;
      v[0] = (short)f2bf(a.x * 0.125f); v[1] = (short)f2bf(a.y * 0.125f);
      v[2] = (short)f2bf(a.z * 0.125f); v[3] = (short)f2bf(a.w * 0.125f);
      v[4] = (short)f2bf(c.x * 0.125f); v[5] = (short)f2bf(c.y * 0.125f);
      v[6] = (short)f2bf(c.z * 0.125f); v[7] = (short)f2bf(c.w * 0.125f);
      qf[kc] = v;
    }
  }

  // ---- staging geometry (fixed per thread across tiles) ----
  int skey = tid >> 2;            // 0..63
  int sd0  = (tid & 3) << 4;      // 0,16,32,48
  const float* kvbase = qkv + (size_t)b * Nn * 2304 + koff + sd0;
  int kIdx0 = swz(skey, sd0);
  int kIdx1 = swz(skey, sd0 + 8);
  int vIdx[16];
#pragma unroll
  for (int j = 0; j < 16; ++j) vIdx[j] = swz(sd0 + j, skey);

  f32x4 oacc[4];
#pragma unroll
  for (int nt = 0; nt < 4; ++nt) oacc[nt] = (f32x4){0.f, 0.f, 0.f, 0.f};
  float mrow[4] = {-1e30f, -1e30f, -1e30f, -1e30f};
  float lrow[4] = {0.f, 0.f, 0.f, 0.f};

  for (int key0 = 0; key0 < Nn; key0 += 64) {
    __syncthreads();
    // ---- stage K (row-major) and V (transposed) as swizzled bf16 ----
    {
      int gk = key0 + skey;
      float va[16];
      if (gk < Nn) {
        const float* kp = kvbase + (size_t)gk * 2304;
        const float* vp = kp + v_rel;
        float4 a0 = *(const float4*)(kp + 0),  a1 = *(const float4*)(kp + 4);
        float4 a2 = *(const float4*)(kp + 8),  a3 = *(const float4*)(kp + 12);
        *(ushort4*)&Klds[kIdx0]     = make_ushort4(f2bf(a0.x), f2bf(a0.y), f2bf(a0.z), f2bf(a0.w));
        *(ushort4*)&Klds[kIdx0 + 4] = make_ushort4(f2bf(a1.x), f2bf(a1.y), f2bf(a1.z), f2bf(a1.w));
        *(ushort4*)&Klds[kIdx1]     = make_ushort4(f2bf(a2.x), f2bf(a2.y), f2bf(a2.z), f2bf(a2.w));
        *(ushort4*)&Klds[kIdx1 + 4] = make_ushort4(f2bf(a3.x), f2bf(a3.y), f2bf(a3.z), f2bf(a3.w));
        float4 b0 = *(const float4*)(vp + 0),  b1 = *(const float4*)(vp + 4);
        float4 b2 = *(const float4*)(vp + 8),  b3 = *(const float4*)(vp + 12);
        va[0] = b0.x; va[1] = b0.y; va[2]  = b0.z; va[3]  = b0.w;
        va[4] = b1.x; va[5] = b1.y; va[6]  = b1.z; va[7]  = b1.w;
        va[8] = b2.x; va[9] = b2.y; va[10] = b2.z; va[11] = b2.w;
        va[12] = b3.x; va[13] = b3.y; va[14] = b3.z; va[15] = b3.w;
      } else {
        ushort4 z = make_ushort4(0, 0, 0, 0);
        *(ushort4*)&Klds[kIdx0] = z; *(ushort4*)&Klds[kIdx0 + 4] = z;
        *(ushort4*)&Klds[kIdx1] = z; *(ushort4*)&Klds[kIdx1 + 4] = z;
#pragma unroll
        for (int j = 0; j < 16; ++j) va[j] = 0.f;
      }
#pragma unroll
      for (int j = 0; j < 16; ++j) Vlds[vIdx[j]] = f2bf(va[j]);
    }
    __syncthreads();

    // ---- S = Q K^T via MFMA ----
    f32x4 sacc[4];
#pragma unroll
    for (int nt = 0; nt < 4; ++nt) sacc[nt] = (f32x4){0.f, 0.f, 0.f, 0.f};
#pragma unroll
    for (int kc = 0; kc < 2; ++kc) {
#pragma unroll
      for (int nt = 0; nt < 4; ++nt) {
        short8v kb = *(const short8v*)&Klds[swz(nt * 16 + li, kc * 32 + g * 8)];
        sacc[nt] = __builtin_amdgcn_mfma_f32_16x16x32_bf16(qf[kc], kb, sacc[nt], 0, 0, 0);
      }
    }

    // ---- mask + online softmax (C layout: row = g*4+r, col = nt*16+li) ----
    float rmax[4] = {-1e30f, -1e30f, -1e30f, -1e30f};
#pragma unroll
    for (int nt = 0; nt < 4; ++nt) {
      int j = key0 + nt * 16 + li;
#pragma unroll
      for (int r = 0; r < 4; ++r) {
        float s = sacc[nt][r];
        int i = qbase + g * 4 + r;
        if (j >= Nn) {
          s = -1e30f;
        } else {
          float msk;
          if (i < Ss) {
            if (j < Ss)       msk = (j == i) ? 0.f : NEGV;
            else if (j == Ss) msk = NEGV;
            else              msk = (pass == 0) ? abias[((size_t)b * Ss + i) * Ll + (j - Ss - 1)] : 0.f;
          } else {
            msk = (j < Ss) ? NEGV : 0.f;
          }
          s += msk;
        }
        sacc[nt][r] = s;
        rmax[r] = fmaxf(rmax[r], s);
      }
    }
#pragma unroll
    for (int off = 1; off < 16; off <<= 1) {
#pragma unroll
      for (int r = 0; r < 4; ++r) rmax[r] = fmaxf(rmax[r], __shfl_xor(rmax[r], off));
    }
    float fac[4], mnew[4], padd[4];
#pragma unroll
    for (int r = 0; r < 4; ++r) {
      mnew[r] = fmaxf(mrow[r], rmax[r]);
      fac[r] = __expf(mrow[r] - mnew[r]);
      mrow[r] = mnew[r];
      padd[r] = 0.f;
    }
    int pbase = wave * 1024;
#pragma unroll
    for (int nt = 0; nt < 4; ++nt) {
#pragma unroll
      for (int r = 0; r < 4; ++r) {
        float p = __expf(sacc[nt][r] - mnew[r]);
        padd[r] += p;
        Plds[pbase + swz(g * 4 + r, nt * 16 + li)] = f2bf(p);
      }
    }
#pragma unroll
    for (int r = 0; r < 4; ++r) {
      float ps = padd[r];
#pragma unroll
      for (int off = 1; off < 16; off <<= 1) ps += __shfl_xor(ps, off);
      lrow[r] = lrow[r] * fac[r] + ps;
    }
#pragma unroll
    for (int nt = 0; nt < 4; ++nt) {
#pragma unroll
      for (int r = 0; r < 4; ++r) oacc[nt][r] *= fac[r];
    }

    // ---- O += P V via MFMA (P from this wave's LDS tile, V^T rows) ----
#pragma unroll
    for (int kc = 0; kc < 2; ++kc) {
      short8v pa = *(const short8v*)&Plds[pbase + swz(li, kc * 32 + g * 8)];
#pragma unroll
      for (int nt = 0; nt < 4; ++nt) {
        short8v vb = *(const short8v*)&Vlds[swz(nt * 16 + li, kc * 32 + g * 8)];
        oacc[nt] = __builtin_amdgcn_mfma_f32_16x16x32_bf16(pa, vb, oacc[nt], 0, 0, 0);
      }
    }
  }

  // ---- epilogue ----
#pragma unroll
  for (int r = 0; r < 4; ++r) {
    int i = qbase + g * 4 + r;
    if (i >= Nn) continue;
    float inv = 1.0f / lrow[r];
    float* op = outp + ((size_t)b * Nn + i) * Cc + h * 64 + li;
#pragma unroll
    for (int nt = 0; nt < 4; ++nt) op[nt * 16] = oacc[nt][r] * inv;
  }
}

// ---------------- l2norm heads ----------------
__global__ __launch_bounds__(256) void l2norm_sos_kernel(
    const float* __restrict__ Xp, float* __restrict__ out) {
  int r = blockIdx.x;
  int tid = (int)threadIdx.x;
  const float* x = Xp + (size_t)r * 512;
  float v0 = x[tid], v1 = x[tid + 256];
  float s = v0 * v0 + v1 * v1;
  __shared__ float sbuf[4];
  for (int off = 32; off; off >>= 1) s += __shfl_xor(s, off);
  if ((tid & 63) == 0) sbuf[tid >> 6] = s;
  __syncthreads();
  float tot = sbuf[0] + sbuf[1] + sbuf[2] + sbuf[3];
  float inv = 1.0f / fmaxf(sqrtf(tot), 1e-12f);
  out[(size_t)r * 512 + tid]       = v0 * inv;
  out[(size_t)r * 512 + tid + 256] = v1 * inv;
}

__global__ __launch_bounds__(256) void l2norm_img_kernel(
    const float* __restrict__ Xp, float* __restrict__ out) {
  int r = blockIdx.x;           // b*1025 + ti
  int b = r / 1025, ti = r % 1025;
  int tid = (int)threadIdx.x;
  const float* x = Xp + (size_t)r * 512;
  float v0 = x[tid], v1 = x[tid + 256];
  float s = v0 * v0 + v1 * v1;
  __shared__ float sbuf[4];
  for (int off = 32; off; off >>= 1) s += __shfl_xor(s, off);
  if ((tid & 63) == 0) sbuf[tid >> 6] = s;
  __syncthreads();
  float tot = sbuf[0] + sbuf[1] + sbuf[2] + sbuf[3];
  if (ti == 0) return;          // first surgery row (token S) is discarded
  float inv = 1.0f / fmaxf(sqrtf(tot), 1e-12f);
  float* o = out + (size_t)b * 512 * 1024 + (ti - 1);
  o[(size_t)tid * 1024]         = v0 * inv;
  o[(size_t)(tid + 256) * 1024] = v1 * inv;
}

extern "C" void kernel_launch(void* const* d_in, const int* in_sizes, int n_in,
                              void* d_out, int out_size, void* d_ws, size_t ws_size,
                              hipStream_t stream) {
  const float* cls      = (const float*)d_in[0];
  const float* pix      = (const float*)d_in[1];
  const float* sur      = (const float*)d_in[2];
  const float* abias    = (const float*)d_in[3];
  const float* qkv_w    = (const float*)d_in[4];
  const float* qkv_b    = (const float*)d_in[5];
  const float* proj_w   = (const float*)d_in[6];
  const float* proj_b   = (const float*)d_in[7];
  const float* ln1_w    = (const float*)d_in[8];
  const float* ln1_b    = (const float*)d_in[9];
  const float* ln2_w    = (const float*)d_in[10];
  const float* ln2_b    = (const float*)d_in[11];
  const float* fc_w     = (const float*)d_in[12];
  const float* fc_b     = (const float*)d_in[13];
  const float* fc2_w    = (const float*)d_in[14];
  const float* fc2_b    = (const float*)d_in[15];
  const float* lnp_w    = (const float*)d_in[16];
  const float* lnp_b    = (const float*)d_in[17];
  const float* proj_o   = (const float*)d_in[18];
  float* out = (float*)d_out;

  const size_t SZ = (size_t)NB * Nn * Cc;      // 1,728,000
  float* ws  = (float*)d_ws;
  float* xo  = ws;
  float* xs  = xo  + SZ;
  float* tln = xs  + SZ;
  float* big = tln + SZ;                        // qkv (5.18M) / mlp hidden (6.91M)
  float* ao  = big + (size_t)NB * Nn * 4 * Cc;  // attn ORI out
  float* as_ = ao  + SZ;                        // attn SUR out

  assemble_kernel<<<6750, 256, 0, stream>>>(cls, pix, sur, xo, xs);

  for (int l = 0; l < 3; ++l) {
    const float* qw = qkv_w + (size_t)l * 2304 * 768;
    const float* pw = proj_w + (size_t)l * 768 * 768;
    const float* fw = fc_w + (size_t)l * 3072 * 768;
    const float* f2 = fc2_w + (size_t)l * 768 * 3072;

    ln_kernel<<<2250, 256, 0, stream>>>(xo, ln1_w + l * 768, ln1_b + l * 768, tln, Nn, 0);
    gemm_kernel<<<dim3(36, 36), 256, 0, stream>>>(tln, qw, qkv_b + l * 2304, nullptr, big,
                                                  2250, 2304, 768, 0, 0);
    attn_mfma_kernel<<<dim3(18, 24, 2), 256, 0, stream>>>(big, abias, ao, as_);
    gemm_kernel<<<dim3(12, 36), 256, 0, stream>>>(ao, pw, proj_b + l * 768, xo, xo,
                                                  2250, 768, 768, 0, 0);
    gemm_kernel<<<dim3(12, 36), 256, 0, stream>>>(as_, pw, proj_b + l * 768, xs, xs,
                                                  2250, 768, 768, 0, 0);
    ln_kernel<<<2250, 256, 0, stream>>>(xo, ln2_w + l * 768, ln2_b + l * 768, tln, Nn, 0);
    gemm_kernel<<<dim3(48, 36), 256, 0, stream>>>(tln, fw, fc_b + l * 3072, nullptr, big,
                                                  2250, 3072, 768, 0, 1);
    gemm_kernel<<<dim3(12, 36), 256, 0, stream>>>(big, f2, fc2_b + l * 768, xo, xo,
                                                  2250, 768, 3072, 0, 0);
  }

  // heads
  float* sos_ln = tln;
  float* img_ln = tln + (size_t)200 * 768;
  float* sos_pj = big;
  float* img_pj = big + (size_t)200 * 512;
  ln_kernel<<<200, 256, 0, stream>>>(xo, lnp_w, lnp_b, sos_ln, 100, 0);
  ln_kernel<<<2050, 256, 0, stream>>>(xs, lnp_w, lnp_b, img_ln, 1025, 100);
  gemm_kernel<<<dim3(8, 4), 256, 0, stream>>>(sos_ln, proj_o, nullptr, nullptr, sos_pj,
                                              200, 512, 768, 1, 0);
  gemm_kernel<<<dim3(8, 33), 256, 0, stream>>>(img_ln, proj_o, nullptr, nullptr, img_pj,
                                               2050, 512, 768, 1, 0);
  l2norm_sos_kernel<<<200, 256, 0, stream>>>(sos_pj, out);
  l2norm_img_kernel<<<2050, 256, 0, stream>>>(img_pj, out + 102400);
}

// Round 3
// 1109.599 us; speedup vs baseline: 8.7400x; 2.0820x over previous
//
#include <hip/hip_runtime.h>
#include <math.h>

// CLIP surgery RecWithAttnbiasHead — round 3: bf16 MFMA GEMMs everywhere.
// n=2, c=768, H=12, d=64, S=100, L=1024, N=1125, LY=3, out=512.

constexpr int Cc = 768;
constexpr int Ss = 100;
constexpr int Hh = 12;
constexpr int Ll = 1024;
constexpr int Nn = 1125;
constexpr int NB = 2;
constexpr float NEGV = -100.0f;

typedef unsigned short u16;
typedef __attribute__((ext_vector_type(8))) short short8v;
typedef __attribute__((ext_vector_type(8))) unsigned short ushort8v;
typedef __attribute__((ext_vector_type(4))) float f32x4;

__device__ inline u16 f2bf(float f) {
  unsigned u = __builtin_bit_cast(unsigned int, f);
  unsigned r = u + 0x7fffu + ((u >> 16) & 1u);
  return (u16)(r >> 16);
}
__device__ inline float bf2f(u16 v) {
  return __builtin_bit_cast(float, (unsigned int)v << 16);
}

// XOR-swizzled flat index into a [rows][64] bf16 LDS tile (16B-chunk swizzle).
__device__ inline int swz(int row, int col) {
  return (row << 6) + ((((col >> 3) ^ (row & 7)) << 3) | (col & 7));
}

// ---------------- assemble token streams ----------------
__global__ __launch_bounds__(256) void assemble_kernel(
    const float* __restrict__ cls, const float* __restrict__ pix,
    const float* __restrict__ sur, float* __restrict__ xo, float* __restrict__ xs) {
  int idx = blockIdx.x * 256 + (int)threadIdx.x;
  int total = NB * Nn * Cc;
  if (idx >= total) return;
  int ch = idx % Cc;
  int t  = (idx / Cc) % Nn;
  int b  = idx / (Cc * Nn);
  float vo, vs;
  if (t <= Ss) vo = cls[b * Cc + ch];
  else         vo = pix[(size_t)b * Cc * Ll + (size_t)ch * Ll + (t - Ss - 1)];
  if (t < Ss)  vs = sur[b * Cc + ch];
  else         vs = sur[(size_t)(t - Ss) * NB * Cc + b * Cc + ch];
  xo[idx] = vo;
  xs[idx] = vs;
}

// ---------------- fp32 -> bf16 convert ----------------
__global__ __launch_bounds__(256) void cvt_bf16_kernel(
    const float* __restrict__ x, u16* __restrict__ y, int n) {
  int i = (blockIdx.x * 256 + (int)threadIdx.x) * 4;
  if (i >= n) return;
  float4 v = *(const float4*)(x + i);
  u16 o0 = f2bf(v.x), o1 = f2bf(v.y), o2 = f2bf(v.z), o3 = f2bf(v.w);
  *(ushort4*)(y + i) = make_ushort4(o0, o1, o2, o3);
}

// transpose proj_out [768][512] fp32 -> [512][768] bf16
__global__ __launch_bounds__(256) void transpose_po_kernel(
    const float* __restrict__ in, u16* __restrict__ out) {
  int id = blockIdx.x * 256 + (int)threadIdx.x;
  if (id >= 512 * 768) return;
  int nidx = id / 768, k = id - nidx * 768;
  out[id] = f2bf(in[(size_t)k * 512 + nidx]);
}

// ---------------- layer norm (fp32 in, bf16 out, row gather) ----------------
__global__ __launch_bounds__(256) void ln_kernel(
    const float* __restrict__ X, const float* __restrict__ w, const float* __restrict__ b,
    u16* __restrict__ Y, int rows_per_b, int row_off) {
  int r = blockIdx.x;
  int bb = r / rows_per_b;
  int i  = r % rows_per_b;
  const float* x = X + ((size_t)bb * Nn + row_off + i) * Cc;
  u16* y = Y + (size_t)r * Cc;
  int tid = (int)threadIdx.x;
  float v0 = x[tid], v1 = x[tid + 256], v2 = x[tid + 512];
  float s = v0 + v1 + v2;
  __shared__ float sbuf[4];
  for (int off = 32; off; off >>= 1) s += __shfl_xor(s, off);
  if ((tid & 63) == 0) sbuf[tid >> 6] = s;
  __syncthreads();
  float mean = (sbuf[0] + sbuf[1] + sbuf[2] + sbuf[3]) * (1.0f / Cc);
  float d0 = v0 - mean, d1 = v1 - mean, d2 = v2 - mean;
  float q = d0 * d0 + d1 * d1 + d2 * d2;
  __syncthreads();
  for (int off = 32; off; off >>= 1) q += __shfl_xor(q, off);
  if ((tid & 63) == 0) sbuf[tid >> 6] = q;
  __syncthreads();
  float var = (sbuf[0] + sbuf[1] + sbuf[2] + sbuf[3]) * (1.0f / Cc);
  float inv = rsqrtf(var + 1e-5f);
  y[tid]       = f2bf(d0 * inv * w[tid]       + b[tid]);
  y[tid + 256] = f2bf(d1 * inv * w[tid + 256] + b[tid + 256]);
  y[tid + 512] = f2bf(d2 * inv * w[tid + 512] + b[tid + 512]);
}

// ---------------- bf16 MFMA GEMM: out[M,N] = A[M,K] @ B[N,K]^T ----------------
// 128x128 tile, BK=64, 4 waves (2x2 of 64x64). Epilogue: +bias, quickGELU(act),
// +res (fp32), store fp32 (outf) or bf16 (outb).
__global__ __launch_bounds__(256) void gemm_bf16_kernel(
    const u16* __restrict__ A, const u16* __restrict__ B,
    const float* __restrict__ bias, const float* __restrict__ res,
    float* __restrict__ outf, u16* __restrict__ outb,
    int M, int N, int K, int act) {
  __shared__ __align__(16) u16 Als[128 * 64];
  __shared__ __align__(16) u16 Bls[128 * 64];
  int tid = (int)threadIdx.x;
  int wave = tid >> 6, lane = tid & 63, g = lane >> 4, li = lane & 15;
  int wm = wave >> 1, wn = wave & 1;
  int row0 = blockIdx.y * 128, col0 = blockIdx.x * 128;

  // staging geometry: 4 chunks (16B) per thread per matrix; write-side swizzle
  const u16* aptr[4]; const u16* bptr[4]; int dsti[4];
#pragma unroll
  for (int j = 0; j < 4; ++j) {
    int c = tid + j * 256;
    int r = c >> 3, c8 = c & 7;
    dsti[j] = (r << 6) + ((c8 ^ (r & 7)) << 3);
    int ra = row0 + r; if (ra > M - 1) ra = M - 1;
    aptr[j] = A + (size_t)ra * K + (c8 << 3);
    bptr[j] = B + (size_t)(col0 + r) * K + (c8 << 3);
  }

  f32x4 acc[4][4];
#pragma unroll
  for (int mi = 0; mi < 4; ++mi)
#pragma unroll
    for (int ni = 0; ni < 4; ++ni) acc[mi][ni] = (f32x4){0.f, 0.f, 0.f, 0.f};

  for (int k0 = 0; k0 < K; k0 += 64) {
    ushort8v ta[4], tb[4];
#pragma unroll
    for (int j = 0; j < 4; ++j) {
      ta[j] = *(const ushort8v*)(aptr[j] + k0);
      tb[j] = *(const ushort8v*)(bptr[j] + k0);
    }
    __syncthreads();
#pragma unroll
    for (int j = 0; j < 4; ++j) {
      *(ushort8v*)&Als[dsti[j]] = ta[j];
      *(ushort8v*)&Bls[dsti[j]] = tb[j];
    }
    __syncthreads();
#pragma unroll
    for (int kc = 0; kc < 2; ++kc) {
      short8v af[4], bfr[4];
#pragma unroll
      for (int mi = 0; mi < 4; ++mi) {
        int rr = wm * 64 + mi * 16 + li;
        af[mi] = *(const short8v*)&Als[(rr << 6) + (((kc * 4 + g) ^ (rr & 7)) << 3)];
      }
#pragma unroll
      for (int ni = 0; ni < 4; ++ni) {
        int rr = wn * 64 + ni * 16 + li;
        bfr[ni] = *(const short8v*)&Bls[(rr << 6) + (((kc * 4 + g) ^ (rr & 7)) << 3)];
      }
#pragma unroll
      for (int mi = 0; mi < 4; ++mi)
#pragma unroll
        for (int ni = 0; ni < 4; ++ni)
          acc[mi][ni] = __builtin_amdgcn_mfma_f32_16x16x32_bf16(af[mi], bfr[ni], acc[mi][ni], 0, 0, 0);
    }
  }

  // epilogue: D row = g*4 + reg (A row), col = li (B row)
#pragma unroll
  for (int mi = 0; mi < 4; ++mi) {
#pragma unroll
    for (int r = 0; r < 4; ++r) {
      int m = row0 + wm * 64 + mi * 16 + g * 4 + r;
      if (m >= M) continue;
#pragma unroll
      for (int ni = 0; ni < 4; ++ni) {
        int n = col0 + wn * 64 + ni * 16 + li;
        float v = acc[mi][ni][r];
        if (bias) v += bias[n];
        if (act)  v = v / (1.0f + __expf(-1.702f * v));
        if (res)  v += res[(size_t)m * N + n];
        if (outf) outf[(size_t)m * N + n] = v;
        else      outb[(size_t)m * N + n] = f2bf(v);
      }
    }
  }
}

// ---------------- MFMA bf16 flash attention (bf16 qkv in, bf16 out) ----------------
__global__ __launch_bounds__(256) void attn_mfma_kernel(
    const u16* __restrict__ qkv, const float* __restrict__ abias,
    u16* __restrict__ out0, u16* __restrict__ out1) {
  __shared__ __align__(16) u16 Klds[64 * 64];
  __shared__ __align__(16) u16 Vlds[64 * 64];    // transposed [d][key]
  __shared__ __align__(16) u16 Plds[4 * 16 * 64]; // per-wave [16][64]
  int pass = blockIdx.z;
  u16* outp = pass == 0 ? out0 : out1;
  int bh = blockIdx.y;
  int b = bh / Hh, h = bh - b * Hh;
  int tid = (int)threadIdx.x;
  int wave = tid >> 6, lane = tid & 63;
  int g = lane >> 4, li = lane & 15;
  int qbase = blockIdx.x * 64 + wave * 16;
  int qoff = (pass == 0) ? h * 64 : 2 * Cc + h * 64;
  int koff = (pass == 0) ? Cc + h * 64 : 2 * Cc + h * 64;
  int voff = 2 * Cc + h * 64;
  int v_rel = voff - koff;

  // Q fragments (scale by 0.125; exact power-of-2 in bf16)
  short8v qf[2];
  {
    int qrow = qbase + li; if (qrow >= Nn) qrow = Nn - 1;
    const u16* qp = qkv + ((size_t)b * Nn + qrow) * 2304 + qoff;
#pragma unroll
    for (int kc = 0; kc < 2; ++kc) {
      ushort8v v8 = *(const ushort8v*)(qp + kc * 32 + g * 8);
      short8v v;
#pragma unroll
      for (int j = 0; j < 8; ++j) v[j] = (short)f2bf(bf2f(v8[j]) * 0.125f);
      qf[kc] = v;
    }
  }

  int skey = tid >> 2;
  int sd0  = (tid & 3) << 4;
  const u16* kvbase = qkv + (size_t)b * Nn * 2304 + koff + sd0;
  int kIdx0 = swz(skey, sd0);
  int kIdx1 = swz(skey, sd0 + 8);
  int vIdx[16];
#pragma unroll
  for (int j = 0; j < 16; ++j) vIdx[j] = swz(sd0 + j, skey);

  f32x4 oacc[4];
#pragma unroll
  for (int nt = 0; nt < 4; ++nt) oacc[nt] = (f32x4){0.f, 0.f, 0.f, 0.f};
  float mrow[4] = {-1e30f, -1e30f, -1e30f, -1e30f};
  float lrow[4] = {0.f, 0.f, 0.f, 0.f};

  for (int key0 = 0; key0 < Nn; key0 += 64) {
    __syncthreads();
    {
      int gk = key0 + skey;
      if (gk < Nn) {
        const u16* kp = kvbase + (size_t)gk * 2304;
        *(ushort8v*)&Klds[kIdx0] = *(const ushort8v*)kp;
        *(ushort8v*)&Klds[kIdx1] = *(const ushort8v*)(kp + 8);
        const u16* vp = kp + v_rel;
        ushort8v v0 = *(const ushort8v*)vp;
        ushort8v v1 = *(const ushort8v*)(vp + 8);
#pragma unroll
        for (int j = 0; j < 8; ++j) Vlds[vIdx[j]] = v0[j];
#pragma unroll
        for (int j = 0; j < 8; ++j) Vlds[vIdx[j + 8]] = v1[j];
      } else {
        ushort8v z = (ushort8v)0;
        *(ushort8v*)&Klds[kIdx0] = z;
        *(ushort8v*)&Klds[kIdx1] = z;
#pragma unroll
        for (int j = 0; j < 16; ++j) Vlds[vIdx[j]] = 0;
      }
    }
    __syncthreads();

    // S = Q K^T
    f32x4 sacc[4];
#pragma unroll
    for (int nt = 0; nt < 4; ++nt) sacc[nt] = (f32x4){0.f, 0.f, 0.f, 0.f};
#pragma unroll
    for (int kc = 0; kc < 2; ++kc) {
#pragma unroll
      for (int nt = 0; nt < 4; ++nt) {
        short8v kb = *(const short8v*)&Klds[swz(nt * 16 + li, kc * 32 + g * 8)];
        sacc[nt] = __builtin_amdgcn_mfma_f32_16x16x32_bf16(qf[kc], kb, sacc[nt], 0, 0, 0);
      }
    }

    // mask + online softmax
    float rmax[4] = {-1e30f, -1e30f, -1e30f, -1e30f};
#pragma unroll
    for (int nt = 0; nt < 4; ++nt) {
      int j = key0 + nt * 16 + li;
#pragma unroll
      for (int r = 0; r < 4; ++r) {
        float s = sacc[nt][r];
        int i = qbase + g * 4 + r;
        if (j >= Nn) {
          s = -1e30f;
        } else {
          float msk;
          if (i < Ss) {
            if (j < Ss)       msk = (j == i) ? 0.f : NEGV;
            else if (j == Ss) msk = NEGV;
            else              msk = (pass == 0) ? abias[((size_t)b * Ss + i) * Ll + (j - Ss - 1)] : 0.f;
          } else {
            msk = (j < Ss) ? NEGV : 0.f;
          }
          s += msk;
        }
        sacc[nt][r] = s;
        rmax[r] = fmaxf(rmax[r], s);
      }
    }
#pragma unroll
    for (int off = 1; off < 16; off <<= 1) {
#pragma unroll
      for (int r = 0; r < 4; ++r) rmax[r] = fmaxf(rmax[r], __shfl_xor(rmax[r], off));
    }
    float fac[4], mnew[4], padd[4];
#pragma unroll
    for (int r = 0; r < 4; ++r) {
      mnew[r] = fmaxf(mrow[r], rmax[r]);
      fac[r] = __expf(mrow[r] - mnew[r]);
      mrow[r] = mnew[r];
      padd[r] = 0.f;
    }
    int pbase = wave * 1024;
#pragma unroll
    for (int nt = 0; nt < 4; ++nt) {
#pragma unroll
      for (int r = 0; r < 4; ++r) {
        float p = __expf(sacc[nt][r] - mnew[r]);
        padd[r] += p;
        Plds[pbase + swz(g * 4 + r, nt * 16 + li)] = f2bf(p);
      }
    }
#pragma unroll
    for (int r = 0; r < 4; ++r) {
      float ps = padd[r];
#pragma unroll
      for (int off = 1; off < 16; off <<= 1) ps += __shfl_xor(ps, off);
      lrow[r] = lrow[r] * fac[r] + ps;
    }
#pragma unroll
    for (int nt = 0; nt < 4; ++nt) {
#pragma unroll
      for (int r = 0; r < 4; ++r) oacc[nt][r] *= fac[r];
    }

    // O += P V
#pragma unroll
    for (int kc = 0; kc < 2; ++kc) {
      short8v pa = *(const short8v*)&Plds[pbase + swz(li, kc * 32 + g * 8)];
#pragma unroll
      for (int nt = 0; nt < 4; ++nt) {
        short8v vb = *(const short8v*)&Vlds[swz(nt * 16 + li, kc * 32 + g * 8)];
        oacc[nt] = __builtin_amdgcn_mfma_f32_16x16x32_bf16(pa, vb, oacc[nt], 0, 0, 0);
      }
    }
  }

#pragma unroll
  for (int r = 0; r < 4; ++r) {
    int i = qbase + g * 4 + r;
    if (i >= Nn) continue;
    float inv = 1.0f / lrow[r];
    u16* op = outp + ((size_t)b * Nn + i) * Cc + h * 64 + li;
#pragma unroll
    for (int nt = 0; nt < 4; ++nt) op[nt * 16] = f2bf(oacc[nt][r] * inv);
  }
}

// ---------------- l2norm heads ----------------
__global__ __launch_bounds__(256) void l2norm_sos_kernel(
    const float* __restrict__ Xp, float* __restrict__ out) {
  int r = blockIdx.x;
  int tid = (int)threadIdx.x;
  const float* x = Xp + (size_t)r * 512;
  float v0 = x[tid], v1 = x[tid + 256];
  float s = v0 * v0 + v1 * v1;
  __shared__ float sbuf[4];
  for (int off = 32; off; off >>= 1) s += __shfl_xor(s, off);
  if ((tid & 63) == 0) sbuf[tid >> 6] = s;
  __syncthreads();
  float tot = sbuf[0] + sbuf[1] + sbuf[2] + sbuf[3];
  float inv = 1.0f / fmaxf(sqrtf(tot), 1e-12f);
  out[(size_t)r * 512 + tid]       = v0 * inv;
  out[(size_t)r * 512 + tid + 256] = v1 * inv;
}

__global__ __launch_bounds__(256) void l2norm_img_kernel(
    const float* __restrict__ Xp, float* __restrict__ out) {
  int r = blockIdx.x;           // b*1025 + ti
  int b = r / 1025, ti = r % 1025;
  int tid = (int)threadIdx.x;
  const float* x = Xp + (size_t)r * 512;
  float v0 = x[tid], v1 = x[tid + 256];
  float s = v0 * v0 + v1 * v1;
  __shared__ float sbuf[4];
  for (int off = 32; off; off >>= 1) s += __shfl_xor(s, off);
  if ((tid & 63) == 0) sbuf[tid >> 6] = s;
  __syncthreads();
  float tot = sbuf[0] + sbuf[1] + sbuf[2] + sbuf[3];
  if (ti == 0) return;          // first surgery row (token S) is discarded
  float inv = 1.0f / fmaxf(sqrtf(tot), 1e-12f);
  float* o = out + (size_t)b * 512 * 1024 + (ti - 1);
  o[(size_t)tid * 1024]         = v0 * inv;
  o[(size_t)(tid + 256) * 1024] = v1 * inv;
}

extern "C" void kernel_launch(void* const* d_in, const int* in_sizes, int n_in,
                              void* d_out, int out_size, void* d_ws, size_t ws_size,
                              hipStream_t stream) {
  const float* cls      = (const float*)d_in[0];
  const float* pix      = (const float*)d_in[1];
  const float* sur      = (const float*)d_in[2];
  const float* abias    = (const float*)d_in[3];
  const float* qkv_w    = (const float*)d_in[4];
  const float* qkv_b    = (const float*)d_in[5];
  const float* proj_w   = (const float*)d_in[6];
  const float* proj_b   = (const float*)d_in[7];
  const float* ln1_w    = (const float*)d_in[8];
  const float* ln1_b    = (const float*)d_in[9];
  const float* ln2_w    = (const float*)d_in[10];
  const float* ln2_b    = (const float*)d_in[11];
  const float* fc_w     = (const float*)d_in[12];
  const float* fc_b     = (const float*)d_in[13];
  const float* fc2_w    = (const float*)d_in[14];
  const float* fc2_b    = (const float*)d_in[15];
  const float* lnp_w    = (const float*)d_in[16];
  const float* lnp_b    = (const float*)d_in[17];
  const float* proj_o   = (const float*)d_in[18];
  float* out = (float*)d_out;

  const size_t SZ = (size_t)NB * Nn * Cc;      // 1,728,000
  float* xo      = (float*)d_ws;
  float* xs      = xo + SZ;
  float* head_pj = xs + SZ;                     // 2250*512 fp32
  u16* tln_bf = (u16*)(head_pj + 2250 * 512);   // 2250*768
  u16* act_bf = tln_bf + 2250 * 768;            // 2250*3072 (qkv uses 2250*2304)
  u16* ao_bf  = act_bf + 2250 * 3072;           // 2250*768
  u16* as_bf  = ao_bf + 2250 * 768;             // 2250*768
  u16* wq_bf  = as_bf + 2250 * 768;             // 3*2304*768
  u16* wp_bf  = wq_bf + 3 * 2304 * 768;         // 3*768*768
  u16* wf_bf  = wp_bf + 3 * 768 * 768;          // 3*3072*768
  u16* w2_bf  = wf_bf + 3 * 3072 * 768;         // 3*768*3072
  u16* wo_bf  = w2_bf + 3 * 768 * 3072;         // 512*768

  assemble_kernel<<<6750, 256, 0, stream>>>(cls, pix, sur, xo, xs);
  cvt_bf16_kernel<<<5184, 256, 0, stream>>>(qkv_w, wq_bf, 3 * 2304 * 768);
  cvt_bf16_kernel<<<1728, 256, 0, stream>>>(proj_w, wp_bf, 3 * 768 * 768);
  cvt_bf16_kernel<<<6912, 256, 0, stream>>>(fc_w, wf_bf, 3 * 3072 * 768);
  cvt_bf16_kernel<<<6912, 256, 0, stream>>>(fc2_w, w2_bf, 3 * 768 * 3072);
  transpose_po_kernel<<<1536, 256, 0, stream>>>(proj_o, wo_bf);

  for (int l = 0; l < 3; ++l) {
    ln_kernel<<<2250, 256, 0, stream>>>(xo, ln1_w + l * 768, ln1_b + l * 768, tln_bf, Nn, 0);
    gemm_bf16_kernel<<<dim3(18, 18), 256, 0, stream>>>(
        tln_bf, wq_bf + (size_t)l * 2304 * 768, qkv_b + l * 2304,
        nullptr, nullptr, act_bf, 2250, 2304, 768, 0);
    attn_mfma_kernel<<<dim3(18, 24, 2), 256, 0, stream>>>(act_bf, abias, ao_bf, as_bf);
    gemm_bf16_kernel<<<dim3(6, 18), 256, 0, stream>>>(
        ao_bf, wp_bf + (size_t)l * 768 * 768, proj_b + l * 768,
        xo, xo, nullptr, 2250, 768, 768, 0);
    gemm_bf16_kernel<<<dim3(6, 18), 256, 0, stream>>>(
        as_bf, wp_bf + (size_t)l * 768 * 768, proj_b + l * 768,
        xs, xs, nullptr, 2250, 768, 768, 0);
    ln_kernel<<<2250, 256, 0, stream>>>(xo, ln2_w + l * 768, ln2_b + l * 768, tln_bf, Nn, 0);
    gemm_bf16_kernel<<<dim3(24, 18), 256, 0, stream>>>(
        tln_bf, wf_bf + (size_t)l * 3072 * 768, fc_b + l * 3072,
        nullptr, nullptr, act_bf, 2250, 3072, 768, 1);
    gemm_bf16_kernel<<<dim3(6, 18), 256, 0, stream>>>(
        act_bf, w2_bf + (size_t)l * 768 * 3072, fc2_b + l * 768,
        xo, xo, nullptr, 2250, 768, 3072, 0);
  }

  // heads: LN rows gathered contiguously (200 sos rows, then 2050 img rows)
  ln_kernel<<<200, 256, 0, stream>>>(xo, lnp_w, lnp_b, tln_bf, 100, 0);
  ln_kernel<<<2050, 256, 0, stream>>>(xs, lnp_w, lnp_b, tln_bf + 200 * 768, 1025, 100);
  gemm_bf16_kernel<<<dim3(4, 18), 256, 0, stream>>>(
      tln_bf, wo_bf, nullptr, nullptr, head_pj, nullptr, 2250, 512, 768, 0);
  l2norm_sos_kernel<<<200, 256, 0, stream>>>(head_pj, out);
  l2norm_img_kernel<<<2050, 256, 0, stream>>>(head_pj + 200 * 512, out + 102400);
}

// Round 4
// 916.694 us; speedup vs baseline: 10.5792x; 1.2104x over previous
//
#include <hip/hip_runtime.h>
#include <math.h>

// CLIP surgery RecWithAttnbiasHead — round 4:
//  - fused dual-pass flash attention with key-split + combine
//  - 64x128 MFMA GEMM tiles (4 waves x 64x32) for parallelism
//  - proj pair fused via blockIdx.z; weight converts merged
// n=2, c=768, H=12, d=64, S=100, L=1024, N=1125, LY=3, out=512.

constexpr int Cc = 768;
constexpr int Ss = 100;
constexpr int Hh = 12;
constexpr int Ll = 1024;
constexpr int Nn = 1125;
constexpr int NB = 2;
constexpr float NEGV = -100.0f;

typedef unsigned short u16;
typedef __attribute__((ext_vector_type(8))) short short8v;
typedef __attribute__((ext_vector_type(8))) unsigned short ushort8v;
typedef __attribute__((ext_vector_type(4))) float f32x4;

__device__ inline u16 f2bf(float f) {
  unsigned u = __builtin_bit_cast(unsigned int, f);
  unsigned r = u + 0x7fffu + ((u >> 16) & 1u);
  return (u16)(r >> 16);
}
__device__ inline float bf2f(u16 v) {
  return __builtin_bit_cast(float, (unsigned int)v << 16);
}

// XOR-swizzled flat index into a [rows][64] bf16 LDS tile (16B-chunk swizzle).
__device__ inline int swz(int row, int col) {
  return (row << 6) + ((((col >> 3) ^ (row & 7)) << 3) | (col & 7));
}

// ---------------- assemble token streams ----------------
__global__ __launch_bounds__(256) void assemble_kernel(
    const float* __restrict__ cls, const float* __restrict__ pix,
    const float* __restrict__ sur, float* __restrict__ xo, float* __restrict__ xs) {
  int idx = blockIdx.x * 256 + (int)threadIdx.x;
  int total = NB * Nn * Cc;
  if (idx >= total) return;
  int ch = idx % Cc;
  int t  = (idx / Cc) % Nn;
  int b  = idx / (Cc * Nn);
  float vo, vs;
  if (t <= Ss) vo = cls[b * Cc + ch];
  else         vo = pix[(size_t)b * Cc * Ll + (size_t)ch * Ll + (t - Ss - 1)];
  if (t < Ss)  vs = sur[b * Cc + ch];
  else         vs = sur[(size_t)(t - Ss) * NB * Cc + b * Cc + ch];
  xo[idx] = vo;
  xs[idx] = vs;
}

// ---------------- merged fp32 -> bf16 weight convert ----------------
constexpr int CN0 = 3 * 2304 * 768;
constexpr int CN1 = 3 * 768 * 768;
constexpr int CN2 = 3 * 3072 * 768;
constexpr int CN3 = 3 * 768 * 3072;
__global__ __launch_bounds__(256) void cvt4_kernel(
    const float* __restrict__ s0, const float* __restrict__ s1,
    const float* __restrict__ s2, const float* __restrict__ s3,
    u16* __restrict__ dst) {
  int i4 = (blockIdx.x * 256 + (int)threadIdx.x) * 4;
  if (i4 >= CN0 + CN1 + CN2 + CN3) return;
  const float* src; int off;
  if (i4 < CN0)             { src = s0; off = i4; }
  else if (i4 < CN0 + CN1)  { src = s1; off = i4 - CN0; }
  else if (i4 < CN0 + CN1 + CN2) { src = s2; off = i4 - CN0 - CN1; }
  else                      { src = s3; off = i4 - CN0 - CN1 - CN2; }
  float4 v = *(const float4*)(src + off);
  *(ushort4*)(dst + i4) = make_ushort4(f2bf(v.x), f2bf(v.y), f2bf(v.z), f2bf(v.w));
}

// transpose proj_out [768][512] fp32 -> [512][768] bf16
__global__ __launch_bounds__(256) void transpose_po_kernel(
    const float* __restrict__ in, u16* __restrict__ out) {
  int id = blockIdx.x * 256 + (int)threadIdx.x;
  if (id >= 512 * 768) return;
  int nidx = id / 768, k = id - nidx * 768;
  out[id] = f2bf(in[(size_t)k * 512 + nidx]);
}

// ---------------- layer norm (fp32 in, bf16 out, row gather) ----------------
__global__ __launch_bounds__(256) void ln_kernel(
    const float* __restrict__ X, const float* __restrict__ w, const float* __restrict__ b,
    u16* __restrict__ Y, int rows_per_b, int row_off) {
  int r = blockIdx.x;
  int bb = r / rows_per_b;
  int i  = r % rows_per_b;
  const float* x = X + ((size_t)bb * Nn + row_off + i) * Cc;
  u16* y = Y + (size_t)r * Cc;
  int tid = (int)threadIdx.x;
  float v0 = x[tid], v1 = x[tid + 256], v2 = x[tid + 512];
  float s = v0 + v1 + v2;
  __shared__ float sbuf[4];
  for (int off = 32; off; off >>= 1) s += __shfl_xor(s, off);
  if ((tid & 63) == 0) sbuf[tid >> 6] = s;
  __syncthreads();
  float mean = (sbuf[0] + sbuf[1] + sbuf[2] + sbuf[3]) * (1.0f / Cc);
  float d0 = v0 - mean, d1 = v1 - mean, d2 = v2 - mean;
  float q = d0 * d0 + d1 * d1 + d2 * d2;
  __syncthreads();
  for (int off = 32; off; off >>= 1) q += __shfl_xor(q, off);
  if ((tid & 63) == 0) sbuf[tid >> 6] = q;
  __syncthreads();
  float var = (sbuf[0] + sbuf[1] + sbuf[2] + sbuf[3]) * (1.0f / Cc);
  float inv = rsqrtf(var + 1e-5f);
  y[tid]       = f2bf(d0 * inv * w[tid]       + b[tid]);
  y[tid + 256] = f2bf(d1 * inv * w[tid + 256] + b[tid + 256]);
  y[tid + 512] = f2bf(d2 * inv * w[tid + 512] + b[tid + 512]);
}

// ---------------- bf16 MFMA GEMM, 64x128 tile ----------------
// out[M,N] = A[M,K] @ B[N,K]^T (+bias, quickGELU if act, +res).
// 4 waves, each computes 64 rows x 32 cols. z selects (A,res,out) stream pair.
__global__ __launch_bounds__(256) void gemm64_kernel(
    const u16* __restrict__ A0, const u16* __restrict__ A1,
    const u16* __restrict__ B, const float* __restrict__ bias,
    const float* __restrict__ res0, const float* __restrict__ res1,
    float* __restrict__ outf0, float* __restrict__ outf1,
    u16* __restrict__ outb0, u16* __restrict__ outb1,
    int M, int N, int K, int act) {
  __shared__ __align__(16) u16 Als[64 * 64];
  __shared__ __align__(16) u16 Bls[128 * 64];
  int zz = blockIdx.z;
  const u16* A = zz ? A1 : A0;
  const float* res = zz ? res1 : res0;
  float* outf = zz ? outf1 : outf0;
  u16* outb = zz ? outb1 : outb0;
  int tid = (int)threadIdx.x;
  int wave = tid >> 6, lane = tid & 63, g = lane >> 4, li = lane & 15;
  int row0 = blockIdx.y * 64, col0 = blockIdx.x * 128;

  const u16* aptr[2]; int dA[2];
#pragma unroll
  for (int j = 0; j < 2; ++j) {
    int ca = tid + j * 256;
    int r = ca >> 3, c8 = ca & 7;
    dA[j] = (r << 6) + ((c8 ^ (r & 7)) << 3);
    int ra = row0 + r; if (ra > M - 1) ra = M - 1;
    aptr[j] = A + (size_t)ra * K + (c8 << 3);
  }
  const u16* bptr[4]; int dB[4];
#pragma unroll
  for (int j = 0; j < 4; ++j) {
    int cb = tid + j * 256;
    int r = cb >> 3, c8 = cb & 7;
    dB[j] = (r << 6) + ((c8 ^ (r & 7)) << 3);
    bptr[j] = B + (size_t)(col0 + r) * K + (c8 << 3);
  }

  f32x4 acc[4][2];
#pragma unroll
  for (int mi = 0; mi < 4; ++mi)
#pragma unroll
    for (int ni = 0; ni < 2; ++ni) acc[mi][ni] = (f32x4){0.f, 0.f, 0.f, 0.f};

  for (int k0 = 0; k0 < K; k0 += 64) {
    ushort8v ta[2], tb[4];
#pragma unroll
    for (int j = 0; j < 2; ++j) ta[j] = *(const ushort8v*)(aptr[j] + k0);
#pragma unroll
    for (int j = 0; j < 4; ++j) tb[j] = *(const ushort8v*)(bptr[j] + k0);
    __syncthreads();
#pragma unroll
    for (int j = 0; j < 2; ++j) *(ushort8v*)&Als[dA[j]] = ta[j];
#pragma unroll
    for (int j = 0; j < 4; ++j) *(ushort8v*)&Bls[dB[j]] = tb[j];
    __syncthreads();
#pragma unroll
    for (int kc = 0; kc < 2; ++kc) {
      short8v af[4], bf2[2];
#pragma unroll
      for (int mi = 0; mi < 4; ++mi) {
        int rr = mi * 16 + li;
        af[mi] = *(const short8v*)&Als[(rr << 6) + (((kc * 4 + g) ^ (rr & 7)) << 3)];
      }
#pragma unroll
      for (int ni = 0; ni < 2; ++ni) {
        int rb = wave * 32 + ni * 16 + li;
        bf2[ni] = *(const short8v*)&Bls[(rb << 6) + (((kc * 4 + g) ^ (rb & 7)) << 3)];
      }
#pragma unroll
      for (int mi = 0; mi < 4; ++mi)
#pragma unroll
        for (int ni = 0; ni < 2; ++ni)
          acc[mi][ni] = __builtin_amdgcn_mfma_f32_16x16x32_bf16(af[mi], bf2[ni], acc[mi][ni], 0, 0, 0);
    }
  }

#pragma unroll
  for (int mi = 0; mi < 4; ++mi) {
#pragma unroll
    for (int r = 0; r < 4; ++r) {
      int m = row0 + mi * 16 + g * 4 + r;
      if (m >= M) continue;
#pragma unroll
      for (int ni = 0; ni < 2; ++ni) {
        int n = col0 + wave * 32 + ni * 16 + li;
        float v = acc[mi][ni][r];
        if (bias) v += bias[n];
        if (act)  v = v / (1.0f + __expf(-1.702f * v));
        if (res)  v += res[(size_t)m * N + n];
        if (outf) outf[(size_t)m * N + n] = v;
        else      outb[(size_t)m * N + n] = f2bf(v);
      }
    }
  }
}

// ---------------- fused dual-pass flash attention with key-split ----------------
// grid (18 qtiles, 24 bh, 2 keyhalves). Per block: 4 waves x 16 queries.
// pass0 (ORI): S = Q K^T + biased mask; pass1 (SUR): S = Vq V^T + plain mask.
// Emits unnormalized O partials + (m,l) per half; combined by attn_combine.
__global__ __launch_bounds__(256) void attn2_kernel(
    const u16* __restrict__ qkv, const float* __restrict__ abias,
    float* __restrict__ opart, float* __restrict__ mlp) {
  __shared__ __align__(16) u16 Klds[64 * 64];
  __shared__ __align__(16) u16 Vr[64 * 64];
  __shared__ __align__(16) u16 Vt[64 * 64];    // transposed [d][key]
  __shared__ __align__(16) u16 Plds[4 * 16 * 64];
  int z = blockIdx.z;
  int bh = blockIdx.y;
  int b = bh / Hh, h = bh - b * Hh;
  int tid = (int)threadIdx.x;
  int wave = tid >> 6, lane = tid & 63, g = lane >> 4, li = lane & 15;
  int qbase = blockIdx.x * 64 + wave * 16;
  int qoff = h * 64;
  int koff = Cc + h * 64;
  int voff = 2 * Cc + h * 64;

  // A-fragments for both passes (q scaled by d^-0.5 = 0.125)
  short8v qf[2], vqf[2];
  {
    int qrow = qbase + li; if (qrow >= Nn) qrow = Nn - 1;
    const u16* qp = qkv + ((size_t)b * Nn + qrow) * 2304;
#pragma unroll
    for (int kc = 0; kc < 2; ++kc) {
      ushort8v a = *(const ushort8v*)(qp + qoff + kc * 32 + g * 8);
      ushort8v c = *(const ushort8v*)(qp + voff + kc * 32 + g * 8);
      short8v va, vc;
#pragma unroll
      for (int j = 0; j < 8; ++j) {
        va[j] = (short)f2bf(bf2f(a[j]) * 0.125f);
        vc[j] = (short)f2bf(bf2f(c[j]) * 0.125f);
      }
      qf[kc] = va; vqf[kc] = vc;
    }
  }

  int skey = tid >> 2;           // 0..63
  int sd0  = (tid & 3) << 4;     // 0,16,32,48
  int rot  = tid & 3;
  const u16* kbase = qkv + (size_t)b * Nn * 2304;
  int kI0 = swz(skey, sd0), kI1 = swz(skey, sd0 + 8);

  f32x4 o0a[4], o1a[4];
#pragma unroll
  for (int nt = 0; nt < 4; ++nt) { o0a[nt] = (f32x4){0,0,0,0}; o1a[nt] = (f32x4){0,0,0,0}; }
  float m0r[4] = {-1e30f,-1e30f,-1e30f,-1e30f}, l0r[4] = {0,0,0,0};
  float m1r[4] = {-1e30f,-1e30f,-1e30f,-1e30f}, l1r[4] = {0,0,0,0};
  int pbase = wave * 1024;

  for (int t = 0; t < 9; ++t) {
    int key0 = z * 576 + t * 64;
    __syncthreads();
    {
      int gk = key0 + skey;
      if (gk < Nn) {
        const u16* kp = kbase + (size_t)gk * 2304;
        *(ushort8v*)&Klds[kI0] = *(const ushort8v*)(kp + koff + sd0);
        *(ushort8v*)&Klds[kI1] = *(const ushort8v*)(kp + koff + sd0 + 8);
        ushort8v v0 = *(const ushort8v*)(kp + voff + sd0);
        ushort8v v1 = *(const ushort8v*)(kp + voff + sd0 + 8);
        *(ushort8v*)&Vr[kI0] = v0;
        *(ushort8v*)&Vr[kI1] = v1;
        u16 vv[16];
#pragma unroll
        for (int j = 0; j < 8; ++j) { vv[j] = v0[j]; vv[j + 8] = v1[j]; }
#pragma unroll
        for (int mm = 0; mm < 16; ++mm) {
          int jj = (mm + rot) & 15;
          Vt[swz(sd0 + jj, skey)] = vv[jj];
        }
      } else {
        ushort8v zv = (ushort8v)0;
        *(ushort8v*)&Klds[kI0] = zv; *(ushort8v*)&Klds[kI1] = zv;
        *(ushort8v*)&Vr[kI0] = zv;   *(ushort8v*)&Vr[kI1] = zv;
#pragma unroll
        for (int mm = 0; mm < 16; ++mm) Vt[swz(sd0 + mm, skey)] = 0;
      }
    }
    __syncthreads();

#define ATTN_PASS(PASS, AF, BMAT, MR, LR, OA)                                    \
    {                                                                            \
      f32x4 sacc[4];                                                             \
      _Pragma("unroll") for (int nt = 0; nt < 4; ++nt) sacc[nt] = (f32x4){0,0,0,0}; \
      __builtin_amdgcn_s_setprio(1);                                             \
      _Pragma("unroll") for (int kc = 0; kc < 2; ++kc) {                         \
        _Pragma("unroll") for (int nt = 0; nt < 4; ++nt) {                       \
          short8v kb = *(const short8v*)&BMAT[swz(nt * 16 + li, kc * 32 + g * 8)]; \
          sacc[nt] = __builtin_amdgcn_mfma_f32_16x16x32_bf16(AF[kc], kb, sacc[nt], 0, 0, 0); \
        }                                                                        \
      }                                                                          \
      __builtin_amdgcn_s_setprio(0);                                             \
      float rmax[4] = {-1e30f,-1e30f,-1e30f,-1e30f};                             \
      _Pragma("unroll") for (int nt = 0; nt < 4; ++nt) {                         \
        int j = key0 + nt * 16 + li;                                             \
        _Pragma("unroll") for (int r = 0; r < 4; ++r) {                          \
          float s = sacc[nt][r];                                                 \
          int i = qbase + g * 4 + r;                                             \
          if (j >= Nn) {                                                         \
            s = -1e30f;                                                          \
          } else {                                                               \
            float msk;                                                           \
            if (i < Ss) {                                                        \
              if (j < Ss)       msk = (j == i) ? 0.f : NEGV;                     \
              else if (j == Ss) msk = NEGV;                                      \
              else              msk = (PASS == 0) ? abias[((size_t)b * Ss + i) * Ll + (j - Ss - 1)] : 0.f; \
            } else {                                                             \
              msk = (j < Ss) ? NEGV : 0.f;                                       \
            }                                                                    \
            s += msk;                                                            \
          }                                                                      \
          sacc[nt][r] = s;                                                       \
          rmax[r] = fmaxf(rmax[r], s);                                           \
        }                                                                        \
      }                                                                          \
      _Pragma("unroll") for (int off = 1; off < 16; off <<= 1) {                 \
        _Pragma("unroll") for (int r = 0; r < 4; ++r)                            \
          rmax[r] = fmaxf(rmax[r], __shfl_xor(rmax[r], off));                    \
      }                                                                          \
      float fac[4], mnew[4], padd[4];                                            \
      _Pragma("unroll") for (int r = 0; r < 4; ++r) {                            \
        mnew[r] = fmaxf(MR[r], rmax[r]);                                         \
        fac[r] = __expf(MR[r] - mnew[r]);                                        \
        MR[r] = mnew[r];                                                         \
        padd[r] = 0.f;                                                           \
      }                                                                          \
      _Pragma("unroll") for (int nt = 0; nt < 4; ++nt) {                         \
        _Pragma("unroll") for (int r = 0; r < 4; ++r) {                          \
          float p = __expf(sacc[nt][r] - mnew[r]);                               \
          padd[r] += p;                                                          \
          Plds[pbase + swz(g * 4 + r, nt * 16 + li)] = f2bf(p);                  \
        }                                                                        \
      }                                                                          \
      _Pragma("unroll") for (int r = 0; r < 4; ++r) {                            \
        float ps = padd[r];                                                      \
        _Pragma("unroll") for (int off = 1; off < 16; off <<= 1) ps += __shfl_xor(ps, off); \
        LR[r] = LR[r] * fac[r] + ps;                                             \
      }                                                                          \
      _Pragma("unroll") for (int nt = 0; nt < 4; ++nt)                           \
        _Pragma("unroll") for (int r = 0; r < 4; ++r) OA[nt][r] *= fac[r];       \
      __builtin_amdgcn_s_setprio(1);                                             \
      _Pragma("unroll") for (int kc = 0; kc < 2; ++kc) {                         \
        short8v pa = *(const short8v*)&Plds[pbase + swz(li, kc * 32 + g * 8)];   \
        _Pragma("unroll") for (int nt = 0; nt < 4; ++nt) {                       \
          short8v vb = *(const short8v*)&Vt[swz(nt * 16 + li, kc * 32 + g * 8)]; \
          OA[nt] = __builtin_amdgcn_mfma_f32_16x16x32_bf16(pa, vb, OA[nt], 0, 0, 0); \
        }                                                                        \
      }                                                                          \
      __builtin_amdgcn_s_setprio(0);                                             \
    }

    ATTN_PASS(0, qf, Klds, m0r, l0r, o0a)
    ATTN_PASS(1, vqf, Vr, m1r, l1r, o1a)
#undef ATTN_PASS
  }

  // epilogue: unnormalized partials + (m,l)
#pragma unroll
  for (int r = 0; r < 4; ++r) {
    int i = qbase + g * 4 + r;
    if (i >= Nn) continue;
    size_t row = (size_t)b * Nn + i;
    float* op0 = opart + ((size_t)(z * 2 + 0) * NB * Nn + row) * Cc + h * 64 + li;
    float* op1 = opart + ((size_t)(z * 2 + 1) * NB * Nn + row) * Cc + h * 64 + li;
#pragma unroll
    for (int nt = 0; nt < 4; ++nt) {
      op0[nt * 16] = o0a[nt][r];
      op1[nt * 16] = o1a[nt][r];
    }
    if (li == 0) {
      size_t mb0 = ((size_t)(z * 2 + 0) * 24 + bh) * (Nn * 2) + i * 2;
      size_t mb1 = ((size_t)(z * 2 + 1) * 24 + bh) * (Nn * 2) + i * 2;
      mlp[mb0] = m0r[r]; mlp[mb0 + 1] = l0r[r];
      mlp[mb1] = m1r[r]; mlp[mb1 + 1] = l1r[r];
    }
  }
}

// ---------------- combine key-halves ----------------
__global__ __launch_bounds__(256) void attn_combine_kernel(
    const float* __restrict__ opart, const float* __restrict__ mlp,
    u16* __restrict__ ao, u16* __restrict__ as_) {
  int blk = blockIdx.x;
  int pass = blk / (NB * Nn);
  int row = blk - pass * (NB * Nn);
  int b = row / Nn, i = row - b * Nn;
  u16* outp = pass ? as_ : ao;
  int tid = (int)threadIdx.x;
#pragma unroll
  for (int e = 0; e < 3; ++e) {
    int c = tid + e * 256;
    int h = c >> 6;
    int bh = b * Hh + h;
    size_t mb0 = ((size_t)(0 * 2 + pass) * 24 + bh) * (Nn * 2) + i * 2;
    size_t mb1 = ((size_t)(1 * 2 + pass) * 24 + bh) * (Nn * 2) + i * 2;
    float m0 = mlp[mb0], l0 = mlp[mb0 + 1];
    float m1 = mlp[mb1], l1 = mlp[mb1 + 1];
    float ms = fmaxf(m0, m1);
    float w0 = __expf(m0 - ms), w1 = __expf(m1 - ms);
    float L = l0 * w0 + l1 * w1;
    float v0 = opart[((size_t)(0 * 2 + pass) * NB * Nn + row) * Cc + c];
    float v1 = opart[((size_t)(1 * 2 + pass) * NB * Nn + row) * Cc + c];
    outp[(size_t)row * Cc + c] = f2bf((v0 * w0 + v1 * w1) / L);
  }
}

// ---------------- l2norm heads ----------------
__global__ __launch_bounds__(256) void l2norm_sos_kernel(
    const float* __restrict__ Xp, float* __restrict__ out) {
  int r = blockIdx.x;
  int tid = (int)threadIdx.x;
  const float* x = Xp + (size_t)r * 512;
  float v0 = x[tid], v1 = x[tid + 256];
  float s = v0 * v0 + v1 * v1;
  __shared__ float sbuf[4];
  for (int off = 32; off; off >>= 1) s += __shfl_xor(s, off);
  if ((tid & 63) == 0) sbuf[tid >> 6] = s;
  __syncthreads();
  float tot = sbuf[0] + sbuf[1] + sbuf[2] + sbuf[3];
  float inv = 1.0f / fmaxf(sqrtf(tot), 1e-12f);
  out[(size_t)r * 512 + tid]       = v0 * inv;
  out[(size_t)r * 512 + tid + 256] = v1 * inv;
}

__global__ __launch_bounds__(256) void l2norm_img_kernel(
    const float* __restrict__ Xp, float* __restrict__ out) {
  int r = blockIdx.x;           // b*1025 + ti
  int b = r / 1025, ti = r % 1025;
  int tid = (int)threadIdx.x;
  const float* x = Xp + (size_t)r * 512;
  float v0 = x[tid], v1 = x[tid + 256];
  float s = v0 * v0 + v1 * v1;
  __shared__ float sbuf[4];
  for (int off = 32; off; off >>= 1) s += __shfl_xor(s, off);
  if ((tid & 63) == 0) sbuf[tid >> 6] = s;
  __syncthreads();
  float tot = sbuf[0] + sbuf[1] + sbuf[2] + sbuf[3];
  if (ti == 0) return;          // first surgery row (token S) is discarded
  float inv = 1.0f / fmaxf(sqrtf(tot), 1e-12f);
  float* o = out + (size_t)b * 512 * 1024 + (ti - 1);
  o[(size_t)tid * 1024]         = v0 * inv;
  o[(size_t)(tid + 256) * 1024] = v1 * inv;
}

extern "C" void kernel_launch(void* const* d_in, const int* in_sizes, int n_in,
                              void* d_out, int out_size, void* d_ws, size_t ws_size,
                              hipStream_t stream) {
  const float* cls      = (const float*)d_in[0];
  const float* pix      = (const float*)d_in[1];
  const float* sur      = (const float*)d_in[2];
  const float* abias    = (const float*)d_in[3];
  const float* qkv_w    = (const float*)d_in[4];
  const float* qkv_b    = (const float*)d_in[5];
  const float* proj_w   = (const float*)d_in[6];
  const float* proj_b   = (const float*)d_in[7];
  const float* ln1_w    = (const float*)d_in[8];
  const float* ln1_b    = (const float*)d_in[9];
  const float* ln2_w    = (const float*)d_in[10];
  const float* ln2_b    = (const float*)d_in[11];
  const float* fc_w     = (const float*)d_in[12];
  const float* fc_b     = (const float*)d_in[13];
  const float* fc2_w    = (const float*)d_in[14];
  const float* fc2_b    = (const float*)d_in[15];
  const float* lnp_w    = (const float*)d_in[16];
  const float* lnp_b    = (const float*)d_in[17];
  const float* proj_o   = (const float*)d_in[18];
  float* out = (float*)d_out;

  const size_t SZ = (size_t)NB * Nn * Cc;        // 1,728,000
  float* xo    = (float*)d_ws;
  float* xs    = xo + SZ;
  float* opart = xs + SZ;                         // 4*2250*768 f32
  float* mlp   = opart + (size_t)4 * 2250 * 768;  // 96*2250 f32
  float* head_pj = opart;                         // reused at head phase
  u16* tln_bf = (u16*)(mlp + 96 * 2250);          // 2250*768
  u16* act_bf = tln_bf + (size_t)2250 * 768;      // 2250*3072
  u16* ao_bf  = act_bf + (size_t)2250 * 3072;     // 2250*768
  u16* as_bf  = ao_bf + (size_t)2250 * 768;       // 2250*768
  u16* wq_bf  = as_bf + (size_t)2250 * 768;       // 3*2304*768
  u16* wp_bf  = wq_bf + (size_t)CN0;              // 3*768*768
  u16* wf_bf  = wp_bf + (size_t)CN1;              // 3*3072*768
  u16* w2_bf  = wf_bf + (size_t)CN2;              // 3*768*3072
  u16* wo_bf  = w2_bf + (size_t)CN3;              // 512*768

  assemble_kernel<<<6750, 256, 0, stream>>>(cls, pix, sur, xo, xs);
  cvt4_kernel<<<20736, 256, 0, stream>>>(qkv_w, proj_w, fc_w, fc2_w, wq_bf);
  transpose_po_kernel<<<1536, 256, 0, stream>>>(proj_o, wo_bf);

  for (int l = 0; l < 3; ++l) {
    ln_kernel<<<2250, 256, 0, stream>>>(xo, ln1_w + l * 768, ln1_b + l * 768, tln_bf, Nn, 0);
    gemm64_kernel<<<dim3(18, 36, 1), 256, 0, stream>>>(
        tln_bf, tln_bf, wq_bf + (size_t)l * 2304 * 768, qkv_b + l * 2304,
        nullptr, nullptr, nullptr, nullptr, act_bf, act_bf, 2250, 2304, 768, 0);
    attn2_kernel<<<dim3(18, 24, 2), 256, 0, stream>>>(act_bf, abias, opart, mlp);
    attn_combine_kernel<<<4500, 256, 0, stream>>>(opart, mlp, ao_bf, as_bf);
    gemm64_kernel<<<dim3(6, 36, 2), 256, 0, stream>>>(
        ao_bf, as_bf, wp_bf + (size_t)l * 768 * 768, proj_b + l * 768,
        xo, xs, xo, xs, nullptr, nullptr, 2250, 768, 768, 0);
    ln_kernel<<<2250, 256, 0, stream>>>(xo, ln2_w + l * 768, ln2_b + l * 768, tln_bf, Nn, 0);
    gemm64_kernel<<<dim3(24, 36, 1), 256, 0, stream>>>(
        tln_bf, tln_bf, wf_bf + (size_t)l * 3072 * 768, fc_b + l * 3072,
        nullptr, nullptr, nullptr, nullptr, act_bf, act_bf, 2250, 3072, 768, 1);
    gemm64_kernel<<<dim3(6, 36, 1), 256, 0, stream>>>(
        act_bf, act_bf, w2_bf + (size_t)l * 768 * 3072, fc2_b + l * 768,
        xo, xo, xo, xo, nullptr, nullptr, 2250, 768, 3072, 0);
  }

  // heads
  ln_kernel<<<200, 256, 0, stream>>>(xo, lnp_w, lnp_b, tln_bf, 100, 0);
  ln_kernel<<<2050, 256, 0, stream>>>(xs, lnp_w, lnp_b, tln_bf + 200 * 768, 1025, 100);
  gemm64_kernel<<<dim3(4, 36, 1), 256, 0, stream>>>(
      tln_bf, tln_bf, wo_bf, nullptr,
      nullptr, nullptr, head_pj, head_pj, nullptr, nullptr, 2250, 512, 768, 0);
  l2norm_sos_kernel<<<200, 256, 0, stream>>>(head_pj, out);
  l2norm_img_kernel<<<2050, 256, 0, stream>>>(head_pj + 200 * 512, out + 102400);
}